// Round 1
// baseline (793.466 us; speedup 1.0000x reference)
//
#include <hip/hip_runtime.h>

#define GRID   512
#define BLOCK  512
#define BATCH  16384
#define NJ     25
#define DEPTH  256
#define ITERS  (BATCH / GRID)   // 32

typedef short s16x8 __attribute__((ext_vector_type(8)));
typedef short s16x4 __attribute__((ext_vector_type(4)));
typedef float f32x4 __attribute__((ext_vector_type(4)));

// fp32 -> bf16 round-to-nearest-even
__device__ __forceinline__ short f2bf(float f) {
  union { float f; unsigned u; } c; c.f = f;
  unsigned r = (c.u + 0x7FFFu + ((c.u >> 16) & 1u)) >> 16;
  return (short)r;
}

#define MFMA(a, b, c) __builtin_amdgcn_mfma_f32_16x16x32_bf16((a), (b), (c), 0, 0, 0)

// 8 waves/block; wave wv owns output cols [32*wv, 32*wv+32).
// Iteration-level double buffer: next batch element's A loads issue at the
// top of the body, convert+LDS-write at the bottom -> full-body latency hiding.
__global__ __launch_bounds__(BLOCK, 4)
void geo_gcn_fused(const float* __restrict__ x,
                   const float* __restrict__ w,
                   float* __restrict__ out)
{
  // pitch 264 shorts = 528 B = 132 dwords -> +4 banks/row skew (2-way max, free)
  __shared__ short As[2][32][264];  // 33792 B
  __shared__ short Ps[32][40];      //  2560 B
  __shared__ float S3[32][33];      //  4224 B
  __shared__ short Yt[8][32][40];   // 20480 B   -> 61056 B total (2 blocks/CU fit)

  const int tid  = threadIdx.x;
  const int wv   = tid >> 6;        // 0..7
  const int lane = tid & 63;
  const int quad = lane >> 4;
  const int l16  = lane & 15;

  // ---- persistent W fragments: wf[ks][td][j] = W[ks*32+quad*8+j][wv*32+td*16+l16]
  // 16 s16x8 = 64 VGPRs (half of the old kernel's 128) ----
  s16x8 wf[8][2];
  {
    const int ncol = wv * 32 + l16;
#pragma unroll
    for (int ks = 0; ks < 8; ++ks)
#pragma unroll
      for (int td = 0; td < 2; ++td) {
        const float* wp = w + (size_t)(ks * 32 + quad * 8) * DEPTH + ncol + td * 16;
#pragma unroll
        for (int j = 0; j < 8; ++j)
          wf[ks][td][j] = f2bf(wp[(size_t)j * DEPTH]);
      }
  }

  const int srow = tid >> 4;        // staging row 0..31 (rows >= NJ stay zero)
  const int sc   = tid & 15;        // 16 threads/row, 16 floats each
  const int tm_s = (wv >> 1) & 1;   // s3 tile owners: waves 0..3
  const int tn_s = wv & 1;

  const float* xrow = x + (size_t)srow * BATCH * DEPTH + sc * 16;

  // ---- prologue: stage batch element 0 into buf 0 ----
  {
    float4 c0 = make_float4(0.f, 0.f, 0.f, 0.f), c1 = c0, c2 = c0, c3 = c0;
    if (srow < NJ) {
      const float* xp = xrow + (size_t)blockIdx.x * DEPTH;
      c0 = *(const float4*)(xp + 0);  c1 = *(const float4*)(xp + 4);
      c2 = *(const float4*)(xp + 8);  c3 = *(const float4*)(xp + 12);
    }
    s16x8 h0, h1;
    h0[0]=f2bf(c0.x); h0[1]=f2bf(c0.y); h0[2]=f2bf(c0.z); h0[3]=f2bf(c0.w);
    h0[4]=f2bf(c1.x); h0[5]=f2bf(c1.y); h0[6]=f2bf(c1.z); h0[7]=f2bf(c1.w);
    h1[0]=f2bf(c2.x); h1[1]=f2bf(c2.y); h1[2]=f2bf(c2.z); h1[3]=f2bf(c2.w);
    h1[4]=f2bf(c3.x); h1[5]=f2bf(c3.y); h1[6]=f2bf(c3.z); h1[7]=f2bf(c3.w);
    *(s16x8*)&As[0][srow][sc * 16]     = h0;
    *(s16x8*)&As[0][srow][sc * 16 + 8] = h1;
  }
  __syncthreads();

  for (int ib = 0; ib < ITERS; ++ib) {
    const int b   = blockIdx.x + GRID * ib;
    const int buf = ib & 1;

    // ---- issue NEXT batch element's global loads now; consume at bottom ----
    float4 n0 = make_float4(0.f, 0.f, 0.f, 0.f), n1 = n0, n2 = n0, n3 = n0;
    if ((ib + 1 < ITERS) && (srow < NJ)) {
      const float* xp = xrow + (size_t)(b + GRID) * DEPTH;
      n0 = *(const float4*)(xp + 0);  n1 = *(const float4*)(xp + 4);
      n2 = *(const float4*)(xp + 8);  n3 = *(const float4*)(xp + 12);
    }

    f32x4 sacc = (f32x4){0.f, 0.f, 0.f, 0.f};
    f32x4 yacc[2][2];
#pragma unroll
    for (int i = 0; i < 2; ++i)
#pragma unroll
      for (int j = 0; j < 2; ++j) yacc[i][j] = (f32x4){0.f, 0.f, 0.f, 0.f};

    // ---- K loop: 8 steps of K=32, whole A already resident in LDS ----
#pragma unroll
    for (int ks = 0; ks < 8; ++ks) {
      s16x8 a0 = *(const s16x8*)&As[buf][l16][ks * 32 + quad * 8];
      s16x8 a1 = *(const s16x8*)&As[buf][16 + l16][ks * 32 + quad * 8];
      if (wv < 4) sacc = MFMA(tm_s ? a1 : a0, tn_s ? a1 : a0, sacc);
      yacc[0][0] = MFMA(a0, wf[ks][0], yacc[0][0]);
      yacc[0][1] = MFMA(a0, wf[ks][1], yacc[0][1]);
      yacc[1][0] = MFMA(a1, wf[ks][0], yacc[1][0]);
      yacc[1][1] = MFMA(a1, wf[ks][1], yacc[1][1]);
    }

    // ---- s3 -> LDS (waves 0..3 own the 4 16x16 tiles) ----
    if (wv < 4) {
#pragma unroll
      for (int r = 0; r < 4; ++r)
        S3[tm_s * 16 + quad * 4 + r][tn_s * 16 + l16] = sacc[r];
    }
    __syncthreads();

    // ---- wave-parallel softmax: 8 lanes/row, 3-step shuffle reduce ----
    if (tid < 256) {
      const int row = tid >> 3, c8 = tid & 7;
      float v[4]; float mx = -3.0e38f;
#pragma unroll
      for (int i = 0; i < 4; ++i) {
        const int j = c8 + 8 * i;
        v[i] = (j < NJ) ? S3[row][j] : -3.0e38f;
        mx = fmaxf(mx, v[i]);
      }
      mx = fmaxf(mx, __shfl_xor(mx, 1));
      mx = fmaxf(mx, __shfl_xor(mx, 2));
      mx = fmaxf(mx, __shfl_xor(mx, 4));
      float e[4]; float sum = 0.f;
#pragma unroll
      for (int i = 0; i < 4; ++i) {
        const int j = c8 + 8 * i;
        e[i] = (j < NJ) ? __expf(v[i] - mx) : 0.f;
        sum += e[i];
      }
      sum += __shfl_xor(sum, 1);
      sum += __shfl_xor(sum, 2);
      sum += __shfl_xor(sum, 4);
      const float rinv = 1.0f / sum;
#pragma unroll
      for (int i = 0; i < 4; ++i)
        Ps[row][c8 + 8 * i] = f2bf(e[i] * rinv);   // cols >= NJ get exact 0
    }
    __syncthreads();

    // ---- Y (C-layout) -> Yt[col][m] bf16 (same-wave scratch, no barrier) ----
#pragma unroll
    for (int tm = 0; tm < 2; ++tm)
#pragma unroll
      for (int td = 0; td < 2; ++td) {
        s16x4 hy;
#pragma unroll
        for (int r = 0; r < 4; ++r) hy[r] = f2bf(yacc[tm][td][r]);
        *(s16x4*)&Yt[wv][td * 16 + l16][tm * 16 + quad * 4] = hy;
      }

    // ---- out_strip = P @ Y_strip ----
    s16x8 pf0 = *(const s16x8*)&Ps[l16][quad * 8];
    s16x8 pf1 = *(const s16x8*)&Ps[16 + l16][quad * 8];
    const f32x4 z4 = (f32x4){0.f, 0.f, 0.f, 0.f};
    float* ob = out + (size_t)b * NJ * DEPTH + wv * 32 + l16;
#pragma unroll
    for (int td = 0; td < 2; ++td) {
      s16x8 yb = *(const s16x8*)&Yt[wv][td * 16 + l16][quad * 8];
      f32x4 o0 = MFMA(pf0, yb, z4);
      f32x4 o1 = MFMA(pf1, yb, z4);
#pragma unroll
      for (int r = 0; r < 4; ++r) {
        ob[(size_t)(quad * 4 + r) * DEPTH + td * 16] = o0[r];   // rows 0..15
        const int nr = 16 + quad * 4 + r;                       // rows 16..24
        if (nr < NJ) ob[(size_t)nr * DEPTH + td * 16] = o1[r];
      }
    }

    // ---- convert + write NEXT batch element into the other buffer ----
    if (ib + 1 < ITERS) {
      s16x8 h0, h1;
      h0[0]=f2bf(n0.x); h0[1]=f2bf(n0.y); h0[2]=f2bf(n0.z); h0[3]=f2bf(n0.w);
      h0[4]=f2bf(n1.x); h0[5]=f2bf(n1.y); h0[6]=f2bf(n1.z); h0[7]=f2bf(n1.w);
      h1[0]=f2bf(n2.x); h1[1]=f2bf(n2.y); h1[2]=f2bf(n2.z); h1[3]=f2bf(n2.w);
      h1[4]=f2bf(n3.x); h1[5]=f2bf(n3.y); h1[6]=f2bf(n3.z); h1[7]=f2bf(n3.w);
      *(s16x8*)&As[1 - buf][srow][sc * 16]     = h0;
      *(s16x8*)&As[1 - buf][srow][sc * 16 + 8] = h1;
    }
    __syncthreads();
  }
}

extern "C" void kernel_launch(void* const* d_in, const int* in_sizes, int n_in,
                              void* d_out, int out_size, void* d_ws, size_t ws_size,
                              hipStream_t stream) {
  (void)in_sizes; (void)n_in; (void)out_size; (void)d_ws; (void)ws_size;
  const float* x = (const float*)d_in[0];
  const float* w = (const float*)d_in[1];
  float* out = (float*)d_out;
  geo_gcn_fused<<<dim3(GRID), dim3(BLOCK), 0, stream>>>(x, w, out);
}

// Round 2
// 712.374 us; speedup vs baseline: 1.1138x; 1.1138x over previous
//
#include <hip/hip_runtime.h>

#define GRID   1024
#define BLOCK  256
#define BATCH  16384
#define NJ     25
#define DEPTH  256
#define ITERS  (BATCH / GRID)   // 16

typedef short s16x8 __attribute__((ext_vector_type(8)));
typedef short s16x4 __attribute__((ext_vector_type(4)));
typedef float f32x4 __attribute__((ext_vector_type(4)));

// fp32 -> bf16 round-to-nearest-even
__device__ __forceinline__ short f2bf(float f) {
  union { float f; unsigned u; } c; c.f = f;
  unsigned r = (c.u + 0x7FFFu + ((c.u >> 16) & 1u)) >> 16;
  return (short)r;
}

#define MFMA(a, b, c) __builtin_amdgcn_mfma_f32_16x16x32_bf16((a), (b), (c), 0, 0, 0)

// Round-0 shape (4 waves x 64 output cols, wf[8][4]) + structural latency fixes:
//  - whole-element LDS staging, K-loop barrier-free
//  - 2 barriers/iter, both draining only AGED vmem:
//      barA: after K-loop (prefetch loads ~2K cycles old; prev stores aged too)
//      barB: after staging writes (lgkm only)
//    stores issued LAST, no trailing barrier (drained at next iter's barA).
//  - As XOR-swizzled in 16B chunks: phys_chunk = logical_chunk ^ (row&7),
//    pitch 256 shorts == 0 mod 32 banks -> canonical conflict-free ds_read_b128.
__global__ __launch_bounds__(BLOCK, 2)
void geo_gcn_fused(const float* __restrict__ x,
                   const float* __restrict__ w,
                   float* __restrict__ out)
{
  __shared__ short As[2][32][256];  // 32768 B, swizzled
  __shared__ short Ps[32][40];      //  2560 B
  __shared__ float S3[32][33];      //  4224 B
  __shared__ short Yt[4][64][40];   // 20480 B  -> 60032 B total

  const int tid  = threadIdx.x;
  const int wv   = tid >> 6;        // 0..3, owns cols [64*wv, 64*wv+64)
  const int lane = tid & 63;
  const int quad = lane >> 4;
  const int l16  = lane & 15;

  // ---- persistent W fragments: wf[ks][td][j] = W[ks*32+quad*8+j][wv*64+td*16+l16]
  s16x8 wf[8][4];
  {
    const int ncol = wv * 64 + l16;
#pragma unroll
    for (int ks = 0; ks < 8; ++ks)
#pragma unroll
      for (int td = 0; td < 4; ++td) {
        const float* wp = w + (size_t)(ks * 32 + quad * 8) * DEPTH + ncol + td * 16;
#pragma unroll
        for (int j = 0; j < 8; ++j)
          wf[ks][td][j] = f2bf(wp[(size_t)j * DEPTH]);
      }
  }

  const int tm_s = wv >> 1;         // s3 tile (tm_s, tn_s) per wave
  const int tn_s = wv & 1;
  const int srow = tid >> 3;        // staging row 0..31 (rows >= NJ stay zero)
  const int sq   = tid & 7;         // 8 threads/row, 32 floats each
  const int ssw  = (sq ^ (srow & 7)) * 8;   // swizzled base chunk offset (shorts)

  const float* xb = x + (size_t)srow * BATCH * DEPTH + sq * 8;

  // ---- prologue: stage element blockIdx.x into As[0] ----
  {
    const float* xp = xb + (size_t)blockIdx.x * DEPTH;
#pragma unroll
    for (int c = 0; c < 4; ++c) {
      float4 c0 = make_float4(0.f, 0.f, 0.f, 0.f), c1 = c0;
      if (srow < NJ) {
        c0 = *(const float4*)(xp + c * 64);
        c1 = *(const float4*)(xp + c * 64 + 4);
      }
      s16x8 h;
      h[0]=f2bf(c0.x); h[1]=f2bf(c0.y); h[2]=f2bf(c0.z); h[3]=f2bf(c0.w);
      h[4]=f2bf(c1.x); h[5]=f2bf(c1.y); h[6]=f2bf(c1.z); h[7]=f2bf(c1.w);
      *(s16x8*)&As[0][srow][ssw + c * 64] = h;
    }
  }
  __syncthreads();

  for (int ib = 0; ib < ITERS; ++ib) {
    const int b   = blockIdx.x + GRID * ib;
    const int buf = ib & 1;

    // ---- issue NEXT element's loads now; consumed after barA (aged ~K-loop) ----
    float4 nf[8];
#pragma unroll
    for (int i = 0; i < 8; ++i) nf[i] = make_float4(0.f, 0.f, 0.f, 0.f);
    if ((ib + 1 < ITERS) && (srow < NJ)) {
      const float* xp = xb + (size_t)(b + GRID) * DEPTH;
#pragma unroll
      for (int c = 0; c < 4; ++c) {
        nf[2 * c]     = *(const float4*)(xp + c * 64);
        nf[2 * c + 1] = *(const float4*)(xp + c * 64 + 4);
      }
    }

    f32x4 sacc = (f32x4){0.f, 0.f, 0.f, 0.f};
    f32x4 yacc[2][4];
#pragma unroll
    for (int i = 0; i < 2; ++i)
#pragma unroll
      for (int j = 0; j < 4; ++j) yacc[i][j] = (f32x4){0.f, 0.f, 0.f, 0.f};

    // ---- K loop: 8 x K=32, barrier-free, swizzled conflict-free reads ----
#pragma unroll
    for (int ks = 0; ks < 8; ++ks) {
      const int co = (((ks * 4 + quad) ^ (l16 & 7)) << 3);
      s16x8 a0 = *(const s16x8*)&As[buf][l16][co];
      s16x8 a1 = *(const s16x8*)&As[buf][16 + l16][co];
      sacc = MFMA(tm_s ? a1 : a0, tn_s ? a1 : a0, sacc);
#pragma unroll
      for (int td = 0; td < 4; ++td) {
        yacc[0][td] = MFMA(a0, wf[ks][td], yacc[0][td]);
        yacc[1][td] = MFMA(a1, wf[ks][td], yacc[1][td]);
      }
    }

    // ---- s3 -> LDS ----
#pragma unroll
    for (int r = 0; r < 4; ++r)
      S3[tm_s * 16 + quad * 4 + r][tn_s * 16 + l16] = sacc[r];
    __syncthreads();   // barA: drains prefetch loads (aged) + prev-iter stores (aged)

    // ---- wave-parallel softmax: 8 lanes/row over 32 rows (all 256 threads) ----
    {
      const int row = tid >> 3, c8 = tid & 7;
      float v[4]; float mx = -3.0e38f;
#pragma unroll
      for (int i = 0; i < 4; ++i) {
        const int j = c8 + 8 * i;
        v[i] = (j < NJ) ? S3[row][j] : -3.0e38f;
        mx = fmaxf(mx, v[i]);
      }
      mx = fmaxf(mx, __shfl_xor(mx, 1));
      mx = fmaxf(mx, __shfl_xor(mx, 2));
      mx = fmaxf(mx, __shfl_xor(mx, 4));
      float e[4]; float sum = 0.f;
#pragma unroll
      for (int i = 0; i < 4; ++i) {
        const int j = c8 + 8 * i;
        e[i] = (j < NJ) ? __expf(v[i] - mx) : 0.f;
        sum += e[i];
      }
      sum += __shfl_xor(sum, 1);
      sum += __shfl_xor(sum, 2);
      sum += __shfl_xor(sum, 4);
      const float rinv = 1.0f / sum;
#pragma unroll
      for (int i = 0; i < 4; ++i)
        Ps[row][c8 + 8 * i] = f2bf(e[i] * rinv);   // cols >= NJ get exact 0
    }

    // ---- stage NEXT element into the other buffer (before barB) ----
    if (ib + 1 < ITERS) {
#pragma unroll
      for (int c = 0; c < 4; ++c) {
        s16x8 h;
        h[0]=f2bf(nf[2*c].x);   h[1]=f2bf(nf[2*c].y);
        h[2]=f2bf(nf[2*c].z);   h[3]=f2bf(nf[2*c].w);
        h[4]=f2bf(nf[2*c+1].x); h[5]=f2bf(nf[2*c+1].y);
        h[6]=f2bf(nf[2*c+1].z); h[7]=f2bf(nf[2*c+1].w);
        *(s16x8*)&As[1 - buf][srow][ssw + c * 64] = h;
      }
    }
    __syncthreads();   // barB: LDS-only drain (cheap)

    // ---- Y (C-layout) -> Yt (wave-private, same-wave DS ordering) ----
#pragma unroll
    for (int tm = 0; tm < 2; ++tm)
#pragma unroll
      for (int td = 0; td < 4; ++td) {
        s16x4 hy;
#pragma unroll
        for (int r = 0; r < 4; ++r) hy[r] = f2bf(yacc[tm][td][r]);
        *(s16x4*)&Yt[wv][td * 16 + l16][tm * 16 + quad * 4] = hy;
      }

    // ---- out_strip = P @ Y_strip; stores issued LAST, no trailing barrier ----
    s16x8 pf0 = *(const s16x8*)&Ps[l16][quad * 8];
    s16x8 pf1 = *(const s16x8*)&Ps[16 + l16][quad * 8];
    const f32x4 z4 = (f32x4){0.f, 0.f, 0.f, 0.f};
    float* ob = out + (size_t)b * NJ * DEPTH + wv * 64 + l16;
#pragma unroll
    for (int td = 0; td < 4; ++td) {
      s16x8 yb = *(const s16x8*)&Yt[wv][td * 16 + l16][quad * 8];
      f32x4 o0 = MFMA(pf0, yb, z4);
      f32x4 o1 = MFMA(pf1, yb, z4);
#pragma unroll
      for (int r = 0; r < 4; ++r) {
        ob[(size_t)(quad * 4 + r) * DEPTH + td * 16] = o0[r];   // rows 0..15
        const int nr = 16 + quad * 4 + r;                       // rows 16..24
        if (nr < NJ) ob[(size_t)nr * DEPTH + td * 16] = o1[r];
      }
    }
    // next iteration's As reads are gated by barB; stores drain at next barA.
  }
}

extern "C" void kernel_launch(void* const* d_in, const int* in_sizes, int n_in,
                              void* d_out, int out_size, void* d_ws, size_t ws_size,
                              hipStream_t stream) {
  (void)in_sizes; (void)n_in; (void)out_size; (void)d_ws; (void)ws_size;
  const float* x = (const float*)d_in[0];
  const float* w = (const float*)d_in[1];
  float* out = (float*)d_out;
  geo_gcn_fused<<<dim3(GRID), dim3(BLOCK), 0, stream>>>(x, w, out);
}